// Round 4
// baseline (1223.127 us; speedup 1.0000x reference)
//
#include <hip/hip_runtime.h>

#define LL 128
#define STR 135            // ≡7 (mod 32): strided (stride-STR) LDS accesses are conflict-free
#define NT 1024
#define LARGENEG -1.0e30f

__device__ __forceinline__ float softplus_f(float x) { return log1pf(__expf(x)); }
__device__ __forceinline__ float sigmoid_f(float x) { return 1.0f / (1.0f + __expf(-x)); }

// LDS layout (two 128 x STR float slabs, 138240 B total):
//   Al[r*STR+c], c>=r : A[r][c]   (inside values incl. diagonal)
//   Al[r*STR+c], c< r : S[c][r]   (pre-softplus LSE, transposed; width>=1 only)
//   Gl[r*STR+c], c>=r : G[r][c]   (outside gradients, accumulated via LDS atomics)
extern "C" __global__ __launch_bounds__(NT, 1) void cky_kernel(
    const float* __restrict__ scores,
    const int* __restrict__ seq_lens,
    float* __restrict__ Z_out,
    float* __restrict__ marg_out)
{
    extern __shared__ float smem[];
    float* Al = smem;
    float* Gl = smem + LL * STR;

    const int b   = blockIdx.x;
    const int tid = threadIdx.x;
    const float* s = scores + (size_t)b * LL * LL;
    float* marg = marg_out + (size_t)b * LL * LL;
    const int len = seq_lens[b];   // DP truncated to len: Z and grads only touch spans in [0, len-1]

    // Zero marginal slab (poisoned d_out; everything outside the computed
    // triangle, incl. j >= len, must be exactly 0) and the G accumulator.
    for (int idx = tid; idx < LL * LL; idx += NT) marg[idx] = 0.0f;
    for (int idx = tid; idx < LL * STR; idx += NT) Gl[idx] = 0.0f;

    // Width 0 diagonal.
    if (tid < len) Al[tid * STR + tid] = softplus_f(s[tid * LL + tid]);
    __syncthreads();

    // ---------------- Inside pass (gather + wave reduce) ----------------
    for (int w = 1; w < len; ++w) {
        const int cells = len - w;
        const int cl  = (cells > 1) ? (32 - __clz(cells - 1)) : 0;  // ceil(log2(cells))
        int gsh = 10 - cl; if (gsh > 6) gsh = 6;                     // cells * 2^gsh <= 1024
        const int g    = 1 << gsh;
        const int gid  = tid >> gsh;
        const int lane = tid & (g - 1);
        if (gid < cells) {
            const int i = gid, j = gid + w;
            const float sv = s[i * LL + j];          // prefetch; overlaps k-loop
            const int full = w >> gsh;               // trips where all g lanes are valid (<= 7)
            const int rem  = w & (g - 1);
            float v[8];
            #pragma unroll
            for (int t = 0; t < 8; ++t) v[t] = LARGENEG;
            #pragma unroll
            for (int t = 0; t < 8; ++t) {
                if (t < full || (t == full && lane < rem)) {   // t<full is wave-uniform
                    const int k = i + lane + t * g;
                    v[t] = Al[i * STR + k] + Al[(k + 1) * STR + j];  // row + strided col (both conflict-free)
                }
            }
            float m = LARGENEG;
            #pragma unroll
            for (int t = 0; t < 8; ++t) m = fmaxf(m, v[t]);
            for (int off = g >> 1; off; off >>= 1)
                m = fmaxf(m, __shfl_xor(m, off, 64));
            float sum = 0.0f;
            #pragma unroll
            for (int t = 0; t < 8; ++t)
                if (t <= full) sum += __expf(v[t] - m);   // invalid slots: exp(-1e30)=0
            for (int off = g >> 1; off; off >>= 1)
                sum += __shfl_xor(sum, off, 64);
            if (lane == 0) {
                const float Sij = m + __logf(sum);
                Al[j * STR + i] = Sij;                               // S^T
                Al[i * STR + j] = Sij + softplus_f(sv);              // A
            }
        }
        __syncthreads();
    }

    if (tid == 0) Z_out[b] = Al[0 * STR + (len - 1)];

    // ---------------- Outside pass (scatter via LDS atomics) ----------------
    // Parent (i,J) at width w is final (all its parents have width > w, done in
    // earlier phases). Each split k contributes the SAME term to both children:
    //   t = G[i,J] * exp(A[i,k] + A[k+1,J] - S[i,J])  ->  G[i,k] += t ; G[k+1,J] += t
    for (int w = len - 1; w >= 0; --w) {
        const int cells = len - w;
        const int cl  = (cells > 1) ? (32 - __clz(cells - 1)) : 0;
        int gsh = 10 - cl; if (gsh > 6) gsh = 6;
        const int g    = 1 << gsh;
        const int gid  = tid >> gsh;
        const int lane = tid & (g - 1);
        if (gid < cells) {
            const int i = gid, J = i + w;
            float Gp = Gl[i * STR + J];                  // broadcast read, final at this phase
            if (i == 0 && J == len - 1) Gp += 1.0f;      // seed dZ/dA[0][len-1] = 1
            if (lane == 0)
                marg[i * LL + J] = Gp * sigmoid_f(s[i * LL + J]);
            if (w > 0 && Gp > 0.0f) {                    // uniform per group
                const float SL = Al[J * STR + i] - __logf(Gp);   // S[i,J] - log(Gp); arg <= ~5, safe
                for (int k = i + lane; k < J; k += g) {
                    const float t = __expf(Al[i * STR + k] + Al[(k + 1) * STR + J] - SL);
                    atomicAdd(&Gl[i * STR + k], t);          // left child (i,k)   — contiguous lanes
                    atomicAdd(&Gl[(k + 1) * STR + J], t);    // right child (k+1,J) — stride-STR lanes
                }
            }
        }
        __syncthreads();
    }
}

extern "C" void kernel_launch(void* const* d_in, const int* in_sizes, int n_in,
                              void* d_out, int out_size, void* d_ws, size_t ws_size,
                              hipStream_t stream) {
    const float* scores  = (const float*)d_in[0];
    const int* seq_lens  = (const int*)d_in[1];
    const int B = in_sizes[1];              // 32
    float* out = (float*)d_out;
    float* Z_out = out;                     // B floats
    float* marg  = out + B;                 // B*L*L floats

    const size_t lds_bytes = (size_t)2 * LL * STR * sizeof(float);  // 138240 B
    hipFuncSetAttribute((const void*)cky_kernel,
                        hipFuncAttributeMaxDynamicSharedMemorySize,
                        (int)lds_bytes);
    cky_kernel<<<B, NT, lds_bytes, stream>>>(scores, seq_lens, Z_out, marg);
}

// Round 5
// 434.957 us; speedup vs baseline: 2.8121x; 2.8121x over previous
//
#include <hip/hip_runtime.h>

#define LL 128
#define STR 135            // ≡7 (mod 32): row and stride-STR LDS streams are <=2-way (free)
#define NT 1024
#define LARGENEG -1.0e30f

__device__ __forceinline__ float softplus_f(float x) { return log1pf(__expf(x)); }
__device__ __forceinline__ float sigmoid_f(float x) { return 1.0f / (1.0f + __expf(-x)); }

// LDS layout:
//   Al[r*STR+c], c>=r : A[r][c]    (inside values incl. diagonal)
//   Al[r*STR+c], c< r : S[c][r]    (pre-softplus LSE, transposed; width>=1)
//   Gl[r*STR+c], c> r : left-acc  for child (r,c)          [unique writer/phase]
//   Gl[r*STR+c], c< r : right-acc for child (c,r), transp. [unique writer/phase]
//   DL[r] / DR[r]     : left/right acc for diagonal children (r,r)
// G[i][J] (i<J) = Gl[i*STR+J] + Gl[J*STR+i];  G[i][i] = DL[i] + DR[i].
extern "C" __global__ __launch_bounds__(NT, 1) void cky_kernel(
    const float* __restrict__ scores,
    const int* __restrict__ seq_lens,
    float* __restrict__ Z_out,
    float* __restrict__ marg_out)
{
    extern __shared__ float smem[];
    float* Al = smem;
    float* Gl = smem + LL * STR;
    float* DL = smem + 2 * LL * STR;
    float* DR = DL + LL;

    const int b   = blockIdx.x;
    const int tid = threadIdx.x;
    const float* s = scores + (size_t)b * LL * LL;
    float* marg = marg_out + (size_t)b * LL * LL;
    const int len = seq_lens[b];   // DP truncated to len (gradients outside are exactly 0)

    // Zero marginal slab (poisoned d_out), G accumulators, diagonal accs.
    for (int idx = tid; idx < LL * LL; idx += NT) marg[idx] = 0.0f;
    for (int idx = tid; idx < LL * STR; idx += NT) Gl[idx] = 0.0f;
    if (tid < 2 * LL) DL[tid] = 0.0f;

    // Width 0 diagonal.
    if (tid < len) Al[tid * STR + tid] = softplus_f(s[tid * LL + tid]);
    __syncthreads();

    // ---------------- Inside pass (gather + wave reduce) ----------------
    for (int w = 1; w < len; ++w) {
        const int cells = len - w;
        const int cl  = (cells > 1) ? (32 - __clz(cells - 1)) : 0;  // ceil(log2(cells))
        int gsh = 10 - cl; if (gsh > 6) gsh = 6;                     // cells * 2^gsh <= 1024
        const int g    = 1 << gsh;
        const int gid  = tid >> gsh;
        const int lane = tid & (g - 1);
        if (gid < cells) {
            const int i = gid, j = gid + w;
            const float sv = s[i * LL + j];          // prefetch; overlaps k-loop
            const int full = w >> gsh;               // wave-uniform full trips (<= 7)
            const int rem  = w & (g - 1);
            float v[8];
            #pragma unroll
            for (int t = 0; t < 8; ++t) v[t] = LARGENEG;
            #pragma unroll
            for (int t = 0; t < 8; ++t) {
                if (t < full || (t == full && lane < rem)) {
                    const int k = i + lane + t * g;
                    v[t] = Al[i * STR + k] + Al[(k + 1) * STR + j];
                }
            }
            float m = LARGENEG;
            #pragma unroll
            for (int t = 0; t < 8; ++t) m = fmaxf(m, v[t]);
            for (int off = g >> 1; off; off >>= 1)
                m = fmaxf(m, __shfl_xor(m, off, 64));
            float sum = 0.0f;
            #pragma unroll
            for (int t = 0; t < 8; ++t)
                if (t <= full) sum += __expf(v[t] - m);   // invalid slots contribute 0
            for (int off = g >> 1; off; off >>= 1)
                sum += __shfl_xor(sum, off, 64);
            if (lane == 0) {
                const float Sij = m + __logf(sum);
                Al[j * STR + i] = Sij;                               // S^T
                Al[i * STR + j] = Sij + softplus_f(sv);              // A
            }
        }
        __syncthreads();
    }

    if (tid == 0) Z_out[b] = Al[0 * STR + (len - 1)];

    // ---------------- Outside pass (race-free LDS scatter, no atomics) ----------------
    // Parent (i,J), width w: each split k contributes the SAME term to both children:
    //   t = exp(A[i,k] + A[k+1,J] - S[i,J] + log G[i,J])   (argument <= 0 since G <= 1)
    //   left child (i,k)   -> Gl[i*STR+k]      (or DL[i] if k==i)
    //   right child (k+1,J) -> Gl[J*STR+(k+1)] (or DR[J] if k+1==J)
    // Within a phase every slot has exactly one writer; phases are barrier-separated.
    for (int w = len - 1; w >= 1; --w) {
        const int cells = len - w;
        const int cl  = (cells > 1) ? (32 - __clz(cells - 1)) : 0;
        int gsh = 10 - cl; if (gsh > 6) gsh = 6;
        const int g    = 1 << gsh;
        const int gid  = tid >> gsh;
        const int lane = tid & (g - 1);
        if (gid < cells) {
            const int i = gid, J = i + w;
            float Gp = Gl[i * STR + J] + Gl[J * STR + i];   // finalized at this phase
            if (i == 0 && J == len - 1) Gp += 1.0f;         // seed dZ/dA[0][len-1] = 1
            if (lane == 0)
                marg[i * LL + J] = Gp * sigmoid_f(s[i * LL + J]);
            if (Gp > 0.0f) {
                const float SL = Al[J * STR + i] - __logf(Gp);   // S[i,J] - log(Gp)
                for (int k = i + lane; k < J; k += g) {
                    const float t = __expf(Al[i * STR + k] + Al[(k + 1) * STR + J] - SL);
                    float* lp = (k == i)     ? (DL + i) : (Gl + i * STR + k);
                    float* rp = (k + 1 == J) ? (DR + J) : (Gl + J * STR + (k + 1));
                    *lp += t;
                    *rp += t;
                }
            }
        }
        __syncthreads();
    }

    // Width-0 cells: G[i][i] = DL[i] + DR[i].
    if (tid < len)
        marg[tid * LL + tid] = (DL[tid] + DR[tid]) * sigmoid_f(s[tid * LL + tid]);
}

extern "C" void kernel_launch(void* const* d_in, const int* in_sizes, int n_in,
                              void* d_out, int out_size, void* d_ws, size_t ws_size,
                              hipStream_t stream) {
    const float* scores  = (const float*)d_in[0];
    const int* seq_lens  = (const int*)d_in[1];
    const int B = in_sizes[1];              // 32
    float* out = (float*)d_out;
    float* Z_out = out;                     // B floats
    float* marg  = out + B;                 // B*L*L floats

    const size_t lds_bytes = (size_t)(2 * LL * STR + 2 * LL) * sizeof(float);  // 139264 B
    hipFuncSetAttribute((const void*)cky_kernel,
                        hipFuncAttributeMaxDynamicSharedMemorySize,
                        (int)lds_bytes);
    cky_kernel<<<B, NT, lds_bytes, stream>>>(scores, seq_lens, Z_out, marg);
}